// Round 7
// baseline (316.723 us; speedup 1.0000x reference)
//
#include <hip/hip_runtime.h>
#include <hip/hip_bf16.h>
#include <math.h>

#define DIM 1024
#define HEADS 16
#define HEAD_DIM 64
#define MAXSEQ 4096
#define BATCH 16
#define SEQ_PER_BLK 16
#define NBLK (MAXSEQ / SEQ_PER_BLK)  // 256 seq-blocks per batch
#define TILE 4

// ---------------- Kernel A: QKV projection ----------------
__global__ __launch_bounds__(256) void qkv_proj(
    const float* __restrict__ token,
    const float* __restrict__ Wq, const float* __restrict__ Wk,
    const float* __restrict__ Wv,
    float* __restrict__ out /* 3 x 16 x 1024 */) {
  __shared__ float tok[BATCH * DIM];  // 64 KiB
  for (int idx = threadIdx.x; idx < BATCH * DIM; idx += 256)
    tok[idx] = token[idx];
  __syncthreads();

  const float* W = (blockIdx.y == 0) ? Wq : ((blockIdx.y == 1) ? Wk : Wv);
  float* o = out + (size_t)blockIdx.y * BATCH * DIM;

  const int wave = threadIdx.x >> 6;
  const int lane = threadIdx.x & 63;
  const int i0 = blockIdx.x * 16 + wave * 4;

  float acc[4][16];
#pragma unroll
  for (int ii = 0; ii < 4; ++ii)
#pragma unroll
    for (int b = 0; b < 16; ++b) acc[ii][b] = 0.f;

  for (int t = 0; t < 16; ++t) {
    const int j = t * 64 + lane;
    float tk[16];
#pragma unroll
    for (int b = 0; b < 16; ++b) tk[b] = tok[b * DIM + j];
#pragma unroll
    for (int ii = 0; ii < 4; ++ii) {
      const float w = W[(size_t)(i0 + ii) * DIM + j];
#pragma unroll
      for (int b = 0; b < 16; ++b) acc[ii][b] = fmaf(w, tk[b], acc[ii][b]);
    }
  }

#pragma unroll
  for (int ii = 0; ii < 4; ++ii)
#pragma unroll
    for (int b = 0; b < 16; ++b) {
      float v = acc[ii][b];
#pragma unroll
      for (int m = 32; m >= 1; m >>= 1) v += __shfl_xor(v, m);
      if (lane == 0) o[(size_t)b * DIM + i0 + ii] = v;
    }
}

// ---------------- Kernel B: flash-decode partials, max-occupancy ------------
// grid (NBLK, BATCH) = 4096 blocks (16 blocks/CU), block 256, NO LDS,
// __launch_bounds__(256,8) -> 32 waves/CU resident. Branch-free hot loop:
// only cache rows s < pos are accumulated (the new-token row pos is handled
// in attn_combine), rows are always in-bounds reads (s < MAXSEQ).
// Thread t: head t>>4, dims (t&15)*4..+4.
// partial layout per (b,h,blk): [m, l, acc[64]]  (66 floats)
__global__ __launch_bounds__(256, 8) void attn_partial(
    const float* __restrict__ kc, const float* __restrict__ vc,
    const float* __restrict__ qkv, const int* __restrict__ pos_p,
    float* __restrict__ part) {
  const int blk = blockIdx.x, b = blockIdx.y;
  const int t = threadIdx.x;
  const int h = t >> 4, lq = t & 15;
  const int pos = pos_p[0];
  const int s0 = blk * SEQ_PER_BLK;

  const float* qp    = qkv + (size_t)b * DIM;
  const float* kbase = kc + (size_t)b * MAXSEQ * DIM;
  const float* vbase = vc + (size_t)b * MAXSEQ * DIM;

  const float scale = 0.125f;  // 1/sqrt(64)
  float4 q4 = *(const float4*)(qp + 4 * t);
  q4.x *= scale; q4.y *= scale; q4.z *= scale; q4.w *= scale;

  float m = -INFINITY, lsum = 0.f;
  float4 a4 = make_float4(0.f, 0.f, 0.f, 0.f);

#pragma unroll
  for (int tile = 0; tile < SEQ_PER_BLK / TILE; ++tile) {
    float4 k4[TILE], v4[TILE];
#pragma unroll
    for (int j = 0; j < TILE; ++j) {
      const int s = s0 + tile * TILE + j;  // always < MAXSEQ
      k4[j] = *(const float4*)(kbase + (size_t)s * DIM + 4 * t);
      v4[j] = *(const float4*)(vbase + (size_t)s * DIM + 4 * t);
    }

    float sc[TILE];
#pragma unroll
    for (int j = 0; j < TILE; ++j)
      sc[j] = q4.x * k4[j].x + q4.y * k4[j].y + q4.z * k4[j].z +
              q4.w * k4[j].w;
#pragma unroll
    for (int j = 0; j < TILE; ++j) {
      sc[j] += __shfl_xor(sc[j], 1);
      sc[j] += __shfl_xor(sc[j], 2);
      sc[j] += __shfl_xor(sc[j], 4);
      sc[j] += __shfl_xor(sc[j], 8);
    }
#pragma unroll
    for (int j = 0; j < TILE; ++j)
      if (s0 + tile * TILE + j >= pos) sc[j] = -INFINITY;  // row pos handled in combine

    float tm = fmaxf(fmaxf(sc[0], sc[1]), fmaxf(sc[2], sc[3]));
    const float m_new = fmaxf(m, tm);
    const float corr = (m_new == -INFINITY) ? 1.f : __expf(m - m_new);
    lsum *= corr;
    a4.x *= corr; a4.y *= corr; a4.z *= corr; a4.w *= corr;
    m = m_new;

#pragma unroll
    for (int j = 0; j < TILE; ++j) {
      const float p = (sc[j] == -INFINITY) ? 0.f : __expf(sc[j] - m);
      lsum += p;
      a4.x = fmaf(p, v4[j].x, a4.x);
      a4.y = fmaf(p, v4[j].y, a4.y);
      a4.z = fmaf(p, v4[j].z, a4.z);
      a4.w = fmaf(p, v4[j].w, a4.w);
    }
  }

  const size_t base = (((size_t)(b * HEADS + h)) * NBLK + blk) * 66;
  part[base + 2 + lq * 4 + 0] = a4.x;
  part[base + 2 + lq * 4 + 1] = a4.y;
  part[base + 2 + lq * 4 + 2] = a4.z;
  part[base + 2 + lq * 4 + 3] = a4.w;
  if (lq == 0) { part[base] = m; part[base + 1] = lsum; }
}

// ---------------- Kernel C: combine partials + new-token row ----------------
// One 64-thread block per (b,h). Thread d owns output dim d. Also computes
// the new-token term: s_new = scale * q.k_new, contributing exp(s_new-M)*v_new.
__global__ __launch_bounds__(64) void attn_combine(
    const float* __restrict__ part, const float* __restrict__ qkv,
    const int* __restrict__ pos_p, float* __restrict__ attn) {
  const int bh = blockIdx.x;
  const int b = bh >> 4, h = bh & 15;
  const int d = threadIdx.x;

  const float qd = qkv[(size_t)b * DIM + h * HEAD_DIM + d];
  const float kd = qkv[(size_t)BATCH * DIM + (size_t)b * DIM + h * HEAD_DIM + d];
  const float vd = qkv[2 * (size_t)BATCH * DIM + (size_t)b * DIM + h * HEAD_DIM + d];

  float sn = qd * kd;
  sn += __shfl_xor(sn, 1);
  sn += __shfl_xor(sn, 2);
  sn += __shfl_xor(sn, 4);
  sn += __shfl_xor(sn, 8);
  sn += __shfl_xor(sn, 16);
  sn += __shfl_xor(sn, 32);
  sn *= 0.125f;  // scale; new-token score (row `pos`)

  const float* p0 = part + (size_t)bh * NBLK * 66;
  float M = sn;
#pragma unroll 8
  for (int c = 0; c < NBLK; ++c) M = fmaxf(M, p0[c * 66]);

  const float wn = __expf(sn - M);
  float L = wn;
  float o = wn * vd;
#pragma unroll 8
  for (int c = 0; c < NBLK; ++c) {
    const float mc = p0[c * 66];
    if (mc > -INFINITY) {
      const float w = __expf(mc - M);
      L += p0[c * 66 + 1] * w;
      o = fmaf(p0[c * 66 + 2 + d], w, o);
    }
  }
  attn[(size_t)b * DIM + h * HEAD_DIM + d] = o / L;
}

// ---------------- Kernel D: output projection ----------------
__global__ __launch_bounds__(256) void o_proj(
    const float* __restrict__ attn, const float* __restrict__ Wo,
    float* __restrict__ out) {
  __shared__ float tok[BATCH * DIM];
  for (int idx = threadIdx.x; idx < BATCH * DIM; idx += 256)
    tok[idx] = attn[idx];
  __syncthreads();

  const int wave = threadIdx.x >> 6;
  const int lane = threadIdx.x & 63;
  const int i0 = blockIdx.x * 16 + wave * 4;

  float acc[4][16];
#pragma unroll
  for (int ii = 0; ii < 4; ++ii)
#pragma unroll
    for (int b = 0; b < 16; ++b) acc[ii][b] = 0.f;

  for (int t = 0; t < 16; ++t) {
    const int j = t * 64 + lane;
    float tk[16];
#pragma unroll
    for (int b = 0; b < 16; ++b) tk[b] = tok[b * DIM + j];
#pragma unroll
    for (int ii = 0; ii < 4; ++ii) {
      const float w = Wo[(size_t)(i0 + ii) * DIM + j];
#pragma unroll
      for (int b = 0; b < 16; ++b) acc[ii][b] = fmaf(w, tk[b], acc[ii][b]);
    }
  }

#pragma unroll
  for (int ii = 0; ii < 4; ++ii)
#pragma unroll
    for (int b = 0; b < 16; ++b) {
      float v = acc[ii][b];
#pragma unroll
      for (int m = 32; m >= 1; m >>= 1) v += __shfl_xor(v, m);
      if (lane == 0) out[(size_t)b * DIM + i0 + ii] = v;
    }
}

extern "C" void kernel_launch(void* const* d_in, const int* in_sizes, int n_in,
                              void* d_out, int out_size, void* d_ws, size_t ws_size,
                              hipStream_t stream) {
  const float* token = (const float*)d_in[0];
  const float* kc = (const float*)d_in[1];
  const float* vc = (const float*)d_in[2];
  const float* Wq = (const float*)d_in[3];
  const float* Wk = (const float*)d_in[4];
  const float* Wv = (const float*)d_in[5];
  const float* Wo = (const float*)d_in[6];
  const int* pos = (const int*)d_in[7];
  float* out = (float*)d_out;
  float* ws = (float*)d_ws;

  // workspace layout (floats):
  //  [0, 49152)   : q,k,v projections (3 x 16 x 1024)
  //  then         : attention partials 16*16*NBLK*66  (~17.3 MB)
  //  then         : combined attention output 16 x 1024
  float* qkv = ws;
  float* part = ws + 3 * BATCH * DIM;
  float* attn = part + (size_t)BATCH * HEADS * NBLK * 66;

  hipLaunchKernelGGL(qkv_proj, dim3(64, 3), dim3(256), 0, stream,
                     token, Wq, Wk, Wv, qkv);
  hipLaunchKernelGGL(attn_partial, dim3(NBLK, BATCH), dim3(256), 0,
                     stream, kc, vc, qkv, pos, part);
  hipLaunchKernelGGL(attn_combine, dim3(BATCH * HEADS), dim3(64), 0, stream,
                     part, qkv, pos, attn);
  hipLaunchKernelGGL(o_proj, dim3(64), dim3(256), 0, stream, attn, Wo, out);
  (void)in_sizes; (void)n_in; (void)out_size; (void)ws_size;
}

// Round 8
// 198.163 us; speedup vs baseline: 1.5983x; 1.5983x over previous
//
#include <hip/hip_runtime.h>
#include <hip/hip_bf16.h>
#include <math.h>

#define DIM 1024
#define HEADS 16
#define HEAD_DIM 64
#define MAXSEQ 4096
#define BATCH 16
#define SEQ_PER_BLK 32
#define NBLK (MAXSEQ / SEQ_PER_BLK)  // 128 seq-blocks per batch
#define NTILES (SEQ_PER_BLK / 4)     // 8 tiles of 4 rows

typedef float v4f __attribute__((ext_vector_type(4)));

// un-sinkable 16B global load into a VGPR quad
__device__ __forceinline__ void gl16(v4f& dst, const float* p) {
  asm volatile("global_load_dwordx4 %0, %1, off" : "=v"(dst) : "v"(p)
               : "memory");
}

// wait until <=8 vector-mem ops outstanding; ties the 8 loaded quads so no
// consumer can be scheduled above the wait (rule #18)
#define TILE_WAIT8(K, V)                                                     \
  asm volatile("s_waitcnt vmcnt(8)"                                          \
               : "+v"(K[0]), "+v"(K[1]), "+v"(K[2]), "+v"(K[3]),             \
                 "+v"(V[0]), "+v"(V[1]), "+v"(V[2]), "+v"(V[3])::"memory")
#define TILE_WAIT0(K, V)                                                     \
  asm volatile("s_waitcnt vmcnt(0)"                                          \
               : "+v"(K[0]), "+v"(K[1]), "+v"(K[2]), "+v"(K[3]),             \
                 "+v"(V[0]), "+v"(V[1]), "+v"(V[2]), "+v"(V[3])::"memory")

// ---------------- Kernel A: QKV projection ----------------
__global__ __launch_bounds__(256) void qkv_proj(
    const float* __restrict__ token,
    const float* __restrict__ Wq, const float* __restrict__ Wk,
    const float* __restrict__ Wv,
    float* __restrict__ out /* 3 x 16 x 1024 */) {
  __shared__ float tok[BATCH * DIM];  // 64 KiB
  for (int idx = threadIdx.x; idx < BATCH * DIM; idx += 256)
    tok[idx] = token[idx];
  __syncthreads();

  const float* W = (blockIdx.y == 0) ? Wq : ((blockIdx.y == 1) ? Wk : Wv);
  float* o = out + (size_t)blockIdx.y * BATCH * DIM;

  const int wave = threadIdx.x >> 6;
  const int lane = threadIdx.x & 63;
  const int i0 = blockIdx.x * 16 + wave * 4;

  float acc[4][16];
#pragma unroll
  for (int ii = 0; ii < 4; ++ii)
#pragma unroll
    for (int b = 0; b < 16; ++b) acc[ii][b] = 0.f;

  for (int t = 0; t < 16; ++t) {
    const int j = t * 64 + lane;
    float tk[16];
#pragma unroll
    for (int b = 0; b < 16; ++b) tk[b] = tok[b * DIM + j];
#pragma unroll
    for (int ii = 0; ii < 4; ++ii) {
      const float w = W[(size_t)(i0 + ii) * DIM + j];
#pragma unroll
      for (int b = 0; b < 16; ++b) acc[ii][b] = fmaf(w, tk[b], acc[ii][b]);
    }
  }

#pragma unroll
  for (int ii = 0; ii < 4; ++ii)
#pragma unroll
    for (int b = 0; b < 16; ++b) {
      float v = acc[ii][b];
#pragma unroll
      for (int m = 32; m >= 1; m >>= 1) v += __shfl_xor(v, m);
      if (lane == 0) o[(size_t)b * DIM + i0 + ii] = v;
    }
}

// ---------------- Kernel B: flash-decode partials, asm-pipelined ------------
// grid (NBLK, BATCH) = 2048 blocks, block 256, launch_bounds(256,4).
// Block owns rows [32*blk, 32*blk+32). Thread t covers floats [4t,4t+4) of
// each 4KB row (head t>>4, dims (t&15)*4..+4). Double-buffered 4-row tiles:
// 8 inline-asm global_load_dwordx4 per tile, s_waitcnt vmcnt(8) with the 8
// destination quads tied "+v" so the pipeline cannot be de-scheduled.
// Cache rows s<pos only (row pos = new token handled in combine).
// partial layout per (b,h,blk): [m, l, acc[64]]  (66 floats)
__global__ __launch_bounds__(256, 4) void attn_partial(
    const float* __restrict__ kc, const float* __restrict__ vc,
    const float* __restrict__ qkv, const int* __restrict__ pos_p,
    float* __restrict__ part) {
  const int blk = blockIdx.x, b = blockIdx.y;
  const int t = threadIdx.x;
  const int h = t >> 4, lq = t & 15;
  const int pos = pos_p[0];
  const int s0 = blk * SEQ_PER_BLK;

  const float scale = 0.125f;  // 1/sqrt(64)
  v4f q4 = *(const v4f*)(qkv + (size_t)b * DIM + 4 * t);
  q4 *= scale;  // forces q-load wait before the asm pipeline starts
  __builtin_amdgcn_sched_barrier(0);

  const float* kp = kc + (size_t)b * MAXSEQ * DIM + (size_t)s0 * DIM + 4 * t;
  const float* vp = vc + (size_t)b * MAXSEQ * DIM + (size_t)s0 * DIM + 4 * t;

  v4f kb[2][4], vb[2][4];

  auto stage = [&](int buf) {
#pragma unroll
    for (int r = 0; r < 4; ++r) {
      gl16(kb[buf][r], kp); kp += DIM;
      gl16(vb[buf][r], vp); vp += DIM;
    }
  };

  float m = -INFINITY, lsum = 0.f;
  v4f a4 = {0.f, 0.f, 0.f, 0.f};

  auto compute = [&](int buf, int srow) {
    float sc[4];
#pragma unroll
    for (int r = 0; r < 4; ++r) {
      const v4f k4 = kb[buf][r];
      sc[r] = q4.x * k4.x + q4.y * k4.y + q4.z * k4.z + q4.w * k4.w;
    }
#pragma unroll
    for (int r = 0; r < 4; ++r) {
      sc[r] += __shfl_xor(sc[r], 1);
      sc[r] += __shfl_xor(sc[r], 2);
      sc[r] += __shfl_xor(sc[r], 4);
      sc[r] += __shfl_xor(sc[r], 8);
    }
#pragma unroll
    for (int r = 0; r < 4; ++r)
      if (srow + r >= pos) sc[r] = -INFINITY;  // row pos handled in combine

    const float tm = fmaxf(fmaxf(sc[0], sc[1]), fmaxf(sc[2], sc[3]));
    const float m_new = fmaxf(m, tm);
    const float corr = (m_new == -INFINITY) ? 1.f : __expf(m - m_new);
    lsum *= corr;
    a4 *= corr;
    m = m_new;
#pragma unroll
    for (int r = 0; r < 4; ++r) {
      const float pp = (sc[r] == -INFINITY) ? 0.f : __expf(sc[r] - m);
      lsum += pp;
      a4 += vb[buf][r] * pp;
    }
  };

  stage(0);  // tile 0 -> buf 0
#pragma unroll
  for (int tt = 0; tt < NTILES - 1; ++tt) {
    stage((tt + 1) & 1);                   // issue tile tt+1 (16 outstanding)
    TILE_WAIT8(kb[tt & 1], vb[tt & 1]);    // tile tt landed
    __builtin_amdgcn_sched_barrier(0);
    compute(tt & 1, s0 + tt * 4);
  }
  TILE_WAIT0(kb[(NTILES - 1) & 1], vb[(NTILES - 1) & 1]);
  __builtin_amdgcn_sched_barrier(0);
  compute((NTILES - 1) & 1, s0 + (NTILES - 1) * 4);

  const size_t base = (((size_t)(b * HEADS + h)) * NBLK + blk) * 66;
  part[base + 2 + lq * 4 + 0] = a4.x;
  part[base + 2 + lq * 4 + 1] = a4.y;
  part[base + 2 + lq * 4 + 2] = a4.z;
  part[base + 2 + lq * 4 + 3] = a4.w;
  if (lq == 0) { part[base] = m; part[base + 1] = lsum; }
}

// ---------------- Kernel C: combine partials + new-token row ----------------
// grid 256 = one block per (b,h), 256 threads = 4 waves. Wave g handles
// chunks c = g, g+4, ...; thread d owns output dim d. Coalesced 256B acc
// reads; LDS cross-wave reduction. New-token (row pos) term added here.
__global__ __launch_bounds__(256) void attn_combine(
    const float* __restrict__ part, const float* __restrict__ qkv,
    float* __restrict__ attn) {
  const int bh = blockIdx.x;
  const int b = bh >> 4, hh = bh & 15;
  const int g = threadIdx.x >> 6, d = threadIdx.x & 63;
  const float* p0 = part + (size_t)bh * NBLK * 66;

  const float qd = qkv[(size_t)b * DIM + hh * HEAD_DIM + d];
  const float kd = qkv[(size_t)BATCH * DIM + (size_t)b * DIM + hh * HEAD_DIM + d];
  const float vd = qkv[2 * (size_t)BATCH * DIM + (size_t)b * DIM + hh * HEAD_DIM + d];

  float sn = qd * kd;
  sn += __shfl_xor(sn, 1);
  sn += __shfl_xor(sn, 2);
  sn += __shfl_xor(sn, 4);
  sn += __shfl_xor(sn, 8);
  sn += __shfl_xor(sn, 16);
  sn += __shfl_xor(sn, 32);
  sn *= 0.125f;  // new-token score (row pos)

  float M = sn;
  for (int c = g; c < NBLK; c += 4) M = fmaxf(M, p0[c * 66]);

  __shared__ float sM[4], sL[4], sO[4][64];
  if (d == 0) sM[g] = M;
  __syncthreads();
  M = fmaxf(fmaxf(sM[0], sM[1]), fmaxf(sM[2], sM[3]));

  float L = 0.f, o = 0.f;
  if (g == 0) {
    const float wn = __expf(sn - M);
    L = wn;
    o = wn * vd;
  }
  for (int c = g; c < NBLK; c += 4) {
    const float mc = p0[c * 66];
    if (mc > -INFINITY) {
      const float w = __expf(mc - M);
      L += p0[c * 66 + 1] * w;
      o = fmaf(p0[c * 66 + 2 + d], w, o);
    }
  }
  sO[g][d] = o;
  if (d == 0) sL[g] = L;
  __syncthreads();
  if (g == 0) {
    o = sO[0][d] + sO[1][d] + sO[2][d] + sO[3][d];
    L = sL[0] + sL[1] + sL[2] + sL[3];
    attn[(size_t)b * DIM + hh * HEAD_DIM + d] = o / L;
  }
}

// ---------------- Kernel D: output projection ----------------
__global__ __launch_bounds__(256) void o_proj(
    const float* __restrict__ attn, const float* __restrict__ Wo,
    float* __restrict__ out) {
  __shared__ float tok[BATCH * DIM];
  for (int idx = threadIdx.x; idx < BATCH * DIM; idx += 256)
    tok[idx] = attn[idx];
  __syncthreads();

  const int wave = threadIdx.x >> 6;
  const int lane = threadIdx.x & 63;
  const int i0 = blockIdx.x * 16 + wave * 4;

  float acc[4][16];
#pragma unroll
  for (int ii = 0; ii < 4; ++ii)
#pragma unroll
    for (int b = 0; b < 16; ++b) acc[ii][b] = 0.f;

  for (int t = 0; t < 16; ++t) {
    const int j = t * 64 + lane;
    float tk[16];
#pragma unroll
    for (int b = 0; b < 16; ++b) tk[b] = tok[b * DIM + j];
#pragma unroll
    for (int ii = 0; ii < 4; ++ii) {
      const float w = Wo[(size_t)(i0 + ii) * DIM + j];
#pragma unroll
      for (int b = 0; b < 16; ++b) acc[ii][b] = fmaf(w, tk[b], acc[ii][b]);
    }
  }

#pragma unroll
  for (int ii = 0; ii < 4; ++ii)
#pragma unroll
    for (int b = 0; b < 16; ++b) {
      float v = acc[ii][b];
#pragma unroll
      for (int m = 32; m >= 1; m >>= 1) v += __shfl_xor(v, m);
      if (lane == 0) out[(size_t)b * DIM + i0 + ii] = v;
    }
}

extern "C" void kernel_launch(void* const* d_in, const int* in_sizes, int n_in,
                              void* d_out, int out_size, void* d_ws, size_t ws_size,
                              hipStream_t stream) {
  const float* token = (const float*)d_in[0];
  const float* kc = (const float*)d_in[1];
  const float* vc = (const float*)d_in[2];
  const float* Wq = (const float*)d_in[3];
  const float* Wk = (const float*)d_in[4];
  const float* Wv = (const float*)d_in[5];
  const float* Wo = (const float*)d_in[6];
  const int* pos = (const int*)d_in[7];
  float* out = (float*)d_out;
  float* ws = (float*)d_ws;

  // workspace layout (floats):
  //  [0, 49152)   : q,k,v projections (3 x 16 x 1024)
  //  then         : attention partials 16*16*NBLK*66  (~8.7 MB)
  //  then         : combined attention output 16 x 1024
  float* qkv = ws;
  float* part = ws + 3 * BATCH * DIM;
  float* attn = part + (size_t)BATCH * HEADS * NBLK * 66;

  hipLaunchKernelGGL(qkv_proj, dim3(64, 3), dim3(256), 0, stream,
                     token, Wq, Wk, Wv, qkv);
  hipLaunchKernelGGL(attn_partial, dim3(NBLK, BATCH), dim3(256), 0,
                     stream, kc, vc, qkv, pos, part);
  hipLaunchKernelGGL(attn_combine, dim3(BATCH * HEADS), dim3(256), 0, stream,
                     part, qkv, attn);
  hipLaunchKernelGGL(o_proj, dim3(64), dim3(256), 0, stream, attn, Wo, out);
  (void)in_sizes; (void)n_in; (void)out_size; (void)ws_size;
}

// Round 9
// 174.524 us; speedup vs baseline: 1.8148x; 1.1354x over previous
//
#include <hip/hip_runtime.h>
#include <hip/hip_bf16.h>
#include <math.h>

#define DIM 1024
#define HEADS 16
#define HEAD_DIM 64
#define MAXSEQ 4096
#define BATCH 16
#define NBLKS 32                       // seq-blocks per batch (grid.x)
#define ROWS_PER_BLK (MAXSEQ / NBLKS)  // 128 rows per block
#define ROWS_PER_WAVE (ROWS_PER_BLK / 4)  // 32 rows per wave (128KB stream)
#define NPART (NBLKS * 4)              // 128 partial records per (b,h)

typedef float v4f __attribute__((ext_vector_type(4)));

// un-sinkable 16B global load into a VGPR quad
__device__ __forceinline__ void gl16(v4f& dst, const float* p) {
  asm volatile("global_load_dwordx4 %0, %1, off" : "=v"(dst) : "v"(p)
               : "memory");
}

// wait until <=N vector-mem ops outstanding; ties the 8 quads of one row-pair
// buffer so consumers cannot be hoisted above the wait (rule #18)
#define ROW_WAIT8(K, V)                                                      \
  asm volatile("s_waitcnt vmcnt(8)"                                          \
               : "+v"(K[0]), "+v"(K[1]), "+v"(K[2]), "+v"(K[3]),             \
                 "+v"(V[0]), "+v"(V[1]), "+v"(V[2]), "+v"(V[3])::"memory")
#define ROW_WAIT0(K, V)                                                      \
  asm volatile("s_waitcnt vmcnt(0)"                                          \
               : "+v"(K[0]), "+v"(K[1]), "+v"(K[2]), "+v"(K[3]),             \
                 "+v"(V[0]), "+v"(V[1]), "+v"(V[2]), "+v"(V[3])::"memory")

// ---------------- Kernel A: QKV projection ----------------
__global__ __launch_bounds__(256) void qkv_proj(
    const float* __restrict__ token,
    const float* __restrict__ Wq, const float* __restrict__ Wk,
    const float* __restrict__ Wv,
    float* __restrict__ out /* 3 x 16 x 1024 */) {
  __shared__ float tok[BATCH * DIM];  // 64 KiB
  for (int idx = threadIdx.x; idx < BATCH * DIM; idx += 256)
    tok[idx] = token[idx];
  __syncthreads();

  const float* W = (blockIdx.y == 0) ? Wq : ((blockIdx.y == 1) ? Wk : Wv);
  float* o = out + (size_t)blockIdx.y * BATCH * DIM;

  const int wave = threadIdx.x >> 6;
  const int lane = threadIdx.x & 63;
  const int i0 = blockIdx.x * 16 + wave * 4;

  float acc[4][16];
#pragma unroll
  for (int ii = 0; ii < 4; ++ii)
#pragma unroll
    for (int b = 0; b < 16; ++b) acc[ii][b] = 0.f;

  for (int t = 0; t < 16; ++t) {
    const int j = t * 64 + lane;
    float tk[16];
#pragma unroll
    for (int b = 0; b < 16; ++b) tk[b] = tok[b * DIM + j];
#pragma unroll
    for (int ii = 0; ii < 4; ++ii) {
      const float w = W[(size_t)(i0 + ii) * DIM + j];
#pragma unroll
      for (int b = 0; b < 16; ++b) acc[ii][b] = fmaf(w, tk[b], acc[ii][b]);
    }
  }

#pragma unroll
  for (int ii = 0; ii < 4; ++ii)
#pragma unroll
    for (int b = 0; b < 16; ++b) {
      float v = acc[ii][b];
#pragma unroll
      for (int m = 32; m >= 1; m >>= 1) v += __shfl_xor(v, m);
      if (lane == 0) o[(size_t)b * DIM + i0 + ii] = v;
    }
}

// ---------------- Kernel B: flash-decode partials, full-row waves -----------
// grid (NBLKS, BATCH) = 512 blocks (2/CU), block 256 = 4 independent waves.
// Wave w owns rows [blk*128 + w*32, +32): a private CONTIGUOUS 128 KB stream
// of K and of V, read as FULL 4KB rows (4 back-to-back dwordx4 per row) --
// every DRAM row touched exactly once, sequentially.
// Lane l, chunk i covers head 4i+(l>>4), dims ((l&15)*4..+4): each lane keeps
// 4 head-slots (q/m/l/acc per slot). Score reduce = shfl_xor{1,2,4,8} within
// the 16-lane group. Cache rows s<pos only (row pos handled in combine).
// partial record per (b,h,pblk= blk*4+w): [m, l, acc[64]] (66 floats)
__global__ __launch_bounds__(256, 2) void attn_partial(
    const float* __restrict__ kc, const float* __restrict__ vc,
    const float* __restrict__ qkv, const int* __restrict__ pos_p,
    float* __restrict__ part) {
  const int blk = blockIdx.x, b = blockIdx.y;
  const int t = threadIdx.x;
  const int w = t >> 6, lane = t & 63;
  const int g = lane >> 4, lq = lane & 15;
  const int pos = pos_p[0];
  const int srow0 = blk * ROWS_PER_BLK + w * ROWS_PER_WAVE;

  const float scale = 0.125f;  // 1/sqrt(64)
  v4f q4[4];
#pragma unroll
  for (int i = 0; i < 4; ++i) {
    q4[i] = *(const v4f*)(qkv + (size_t)b * DIM + (4 * i + g) * HEAD_DIM +
                          lq * 4);
    q4[i] *= scale;
  }
  __builtin_amdgcn_sched_barrier(0);

  const float* kp = kc + (size_t)b * MAXSEQ * DIM + (size_t)srow0 * DIM +
                    lane * 4;
  const float* vp = vc + (size_t)b * MAXSEQ * DIM + (size_t)srow0 * DIM +
                    lane * 4;

  v4f k0[4], v0[4], k1[4], v1[4];

#define STAGE(K, V, r)                                                       \
  {                                                                          \
    const float* kr = kp + (size_t)(r)*DIM;                                  \
    const float* vr = vp + (size_t)(r)*DIM;                                  \
    gl16(K[0], kr); gl16(K[1], kr + 256);                                    \
    gl16(K[2], kr + 512); gl16(K[3], kr + 768);                              \
    gl16(V[0], vr); gl16(V[1], vr + 256);                                    \
    gl16(V[2], vr + 512); gl16(V[3], vr + 768);                              \
  }

  float m[4], lsum[4];
  v4f acc[4];
#pragma unroll
  for (int i = 0; i < 4; ++i) {
    m[i] = -INFINITY;
    lsum[i] = 0.f;
    acc[i] = (v4f){0.f, 0.f, 0.f, 0.f};
  }

  auto compute = [&](const v4f (&K)[4], const v4f (&V)[4], int r) {
    const int s = srow0 + r;
    if (s >= pos) return;  // wave-uniform; row pos handled in combine
    float sc[4];
#pragma unroll
    for (int i = 0; i < 4; ++i)
      sc[i] = q4[i].x * K[i].x + q4[i].y * K[i].y + q4[i].z * K[i].z +
              q4[i].w * K[i].w;
#pragma unroll
    for (int i = 0; i < 4; ++i) {
      sc[i] += __shfl_xor(sc[i], 1);
      sc[i] += __shfl_xor(sc[i], 2);
      sc[i] += __shfl_xor(sc[i], 4);
      sc[i] += __shfl_xor(sc[i], 8);
    }
#pragma unroll
    for (int i = 0; i < 4; ++i) {
      const float mn = fmaxf(m[i], sc[i]);
      const float corr = __expf(m[i] - mn);  // exp(-inf)=0 on first row
      const float p = __expf(sc[i] - mn);
      lsum[i] = lsum[i] * corr + p;
      acc[i] = acc[i] * corr + V[i] * p;
      m[i] = mn;
    }
  };

  STAGE(k0, v0, 0);
  STAGE(k1, v1, 1);
#pragma unroll 1
  for (int r = 0; r <= ROWS_PER_WAVE - 4; r += 2) {
    ROW_WAIT8(k0, v0);
    __builtin_amdgcn_sched_barrier(0);
    compute(k0, v0, r);
    STAGE(k0, v0, r + 2);
    ROW_WAIT8(k1, v1);
    __builtin_amdgcn_sched_barrier(0);
    compute(k1, v1, r + 1);
    STAGE(k1, v1, r + 3);
  }
  // epilogue: rows ROWS_PER_WAVE-2 (k0) and ROWS_PER_WAVE-1 (k1)
  ROW_WAIT8(k0, v0);
  __builtin_amdgcn_sched_barrier(0);
  compute(k0, v0, ROWS_PER_WAVE - 2);
  ROW_WAIT0(k1, v1);
  __builtin_amdgcn_sched_barrier(0);
  compute(k1, v1, ROWS_PER_WAVE - 1);
#undef STAGE

  const int pblk = blk * 4 + w;
#pragma unroll
  for (int i = 0; i < 4; ++i) {
    const int head = 4 * i + g;
    const size_t base = (((size_t)(b * HEADS + head)) * NPART + pblk) * 66;
    part[base + 2 + lq * 4 + 0] = acc[i].x;
    part[base + 2 + lq * 4 + 1] = acc[i].y;
    part[base + 2 + lq * 4 + 2] = acc[i].z;
    part[base + 2 + lq * 4 + 3] = acc[i].w;
    if (lq == 0) { part[base] = m[i]; part[base + 1] = lsum[i]; }
  }
}

// ---------------- Kernel C: combine partials + new-token row ----------------
// grid 256 = one block per (b,h), 256 threads = 4 waves. Wave gr handles
// records c = gr, gr+4, ...; thread d owns output dim d. New-token (row pos)
// term computed here from the fresh projections.
__global__ __launch_bounds__(256) void attn_combine(
    const float* __restrict__ part, const float* __restrict__ qkv,
    float* __restrict__ attn) {
  const int bh = blockIdx.x;
  const int b = bh >> 4, hh = bh & 15;
  const int gr = threadIdx.x >> 6, d = threadIdx.x & 63;
  const float* p0 = part + (size_t)bh * NPART * 66;

  const float qd = qkv[(size_t)b * DIM + hh * HEAD_DIM + d];
  const float kd = qkv[(size_t)BATCH * DIM + (size_t)b * DIM + hh * HEAD_DIM + d];
  const float vd = qkv[2 * (size_t)BATCH * DIM + (size_t)b * DIM + hh * HEAD_DIM + d];

  float sn = qd * kd;
  sn += __shfl_xor(sn, 1);
  sn += __shfl_xor(sn, 2);
  sn += __shfl_xor(sn, 4);
  sn += __shfl_xor(sn, 8);
  sn += __shfl_xor(sn, 16);
  sn += __shfl_xor(sn, 32);
  sn *= 0.125f;  // new-token score (row pos)

  float M = sn;
  for (int c = gr; c < NPART; c += 4) M = fmaxf(M, p0[c * 66]);

  __shared__ float sM[4], sL[4], sO[4][64];
  if (d == 0) sM[gr] = M;
  __syncthreads();
  M = fmaxf(fmaxf(sM[0], sM[1]), fmaxf(sM[2], sM[3]));

  float L = 0.f, o = 0.f;
  if (gr == 0) {
    const float wn = __expf(sn - M);
    L = wn;
    o = wn * vd;
  }
  for (int c = gr; c < NPART; c += 4) {
    const float mc = p0[c * 66];
    if (mc > -INFINITY) {
      const float w = __expf(mc - M);
      L += p0[c * 66 + 1] * w;
      o = fmaf(p0[c * 66 + 2 + d], w, o);
    }
  }
  sO[gr][d] = o;
  if (d == 0) sL[gr] = L;
  __syncthreads();
  if (gr == 0) {
    o = sO[0][d] + sO[1][d] + sO[2][d] + sO[3][d];
    L = sL[0] + sL[1] + sL[2] + sL[3];
    attn[(size_t)b * DIM + hh * HEAD_DIM + d] = o / L;
  }
}

// ---------------- Kernel D: output projection ----------------
__global__ __launch_bounds__(256) void o_proj(
    const float* __restrict__ attn, const float* __restrict__ Wo,
    float* __restrict__ out) {
  __shared__ float tok[BATCH * DIM];
  for (int idx = threadIdx.x; idx < BATCH * DIM; idx += 256)
    tok[idx] = attn[idx];
  __syncthreads();

  const int wave = threadIdx.x >> 6;
  const int lane = threadIdx.x & 63;
  const int i0 = blockIdx.x * 16 + wave * 4;

  float acc[4][16];
#pragma unroll
  for (int ii = 0; ii < 4; ++ii)
#pragma unroll
    for (int b = 0; b < 16; ++b) acc[ii][b] = 0.f;

  for (int t = 0; t < 16; ++t) {
    const int j = t * 64 + lane;
    float tk[16];
#pragma unroll
    for (int b = 0; b < 16; ++b) tk[b] = tok[b * DIM + j];
#pragma unroll
    for (int ii = 0; ii < 4; ++ii) {
      const float w = Wo[(size_t)(i0 + ii) * DIM + j];
#pragma unroll
      for (int b = 0; b < 16; ++b) acc[ii][b] = fmaf(w, tk[b], acc[ii][b]);
    }
  }

#pragma unroll
  for (int ii = 0; ii < 4; ++ii)
#pragma unroll
    for (int b = 0; b < 16; ++b) {
      float v = acc[ii][b];
#pragma unroll
      for (int m = 32; m >= 1; m >>= 1) v += __shfl_xor(v, m);
      if (lane == 0) out[(size_t)b * DIM + i0 + ii] = v;
    }
}

extern "C" void kernel_launch(void* const* d_in, const int* in_sizes, int n_in,
                              void* d_out, int out_size, void* d_ws, size_t ws_size,
                              hipStream_t stream) {
  const float* token = (const float*)d_in[0];
  const float* kc = (const float*)d_in[1];
  const float* vc = (const float*)d_in[2];
  const float* Wq = (const float*)d_in[3];
  const float* Wk = (const float*)d_in[4];
  const float* Wv = (const float*)d_in[5];
  const float* Wo = (const float*)d_in[6];
  const int* pos = (const int*)d_in[7];
  float* out = (float*)d_out;
  float* ws = (float*)d_ws;

  // workspace layout (floats):
  //  [0, 49152)   : q,k,v projections (3 x 16 x 1024)
  //  then         : attention partials 16*16*NPART*66  (~8.7 MB)
  //  then         : combined attention output 16 x 1024
  float* qkv = ws;
  float* part = ws + 3 * BATCH * DIM;
  float* attn = part + (size_t)BATCH * HEADS * NPART * 66;

  hipLaunchKernelGGL(qkv_proj, dim3(64, 3), dim3(256), 0, stream,
                     token, Wq, Wk, Wv, qkv);
  hipLaunchKernelGGL(attn_partial, dim3(NBLKS, BATCH), dim3(256), 0,
                     stream, kc, vc, qkv, pos, part);
  hipLaunchKernelGGL(attn_combine, dim3(BATCH * HEADS), dim3(256), 0, stream,
                     part, qkv, attn);
  hipLaunchKernelGGL(o_proj, dim3(64), dim3(256), 0, stream, attn, Wo, out);
  (void)in_sizes; (void)n_in; (void)out_size; (void)ws_size;
}